// Round 5
// baseline (233.391 us; speedup 1.0000x reference)
//
#include <hip/hip_runtime.h>
#include <cstdint>
#include <cstddef>

typedef unsigned short ushort_t;
typedef unsigned int uint_t;

typedef __bf16 bf16x8 __attribute__((ext_vector_type(8)));
typedef float floatx4 __attribute__((ext_vector_type(4)));

#define B_ 16
#define N1_ 4096
#define N2_ 1024
#define C1_ 128
#define C2_ 256
#define DIN_ 384
#define DOUT_ 256
#define M_ (B_ * N1_)  // 65536

// As: row-major [64 rows][384 cols] bf16, +8 elem row pad -> 392 elems.
#define ASTRIDE 392
// HS: row-major [64 rows][256 cols] bf16, +8 elem row pad -> 264 elems.
// Aliases the front of As (33792 B <= 50176 B).
#define HSTRIDE 264

// ---------------- helpers ----------------

__device__ __forceinline__ ushort_t f2bf(float f) {
  unsigned int u = __builtin_bit_cast(unsigned int, f);
  u = (u + 0x7fffu + ((u >> 16) & 1u)) >> 16;  // RNE
  return (ushort_t)u;
}

// ---------------- kernel P: weight swizzle + bf16 convert ----------------
// W1s[t][n][kk] = bf16(W1[t*32+kk][n]) — exact B-fragment order.

__global__ __launch_bounds__(256) void prep_kernel(
    const float* __restrict__ W1, const float* __restrict__ W2,
    ushort_t* __restrict__ W1s, ushort_t* __restrict__ W2s) {
  int e = blockIdx.x * 256 + threadIdx.x;
  if (e < DOUT_ * DIN_) {  // 98304
    int kk = e & 31, n = (e >> 5) & 255, t = e >> 13;
    W1s[e] = f2bf(W1[(size_t)(t * 32 + kk) * DOUT_ + n]);
  }
  if (e < DOUT_ * DOUT_) {  // 65536
    int kk = e & 31, n = (e >> 5) & 255, t = e >> 13;
    W2s[e] = f2bf(W2[(size_t)(t * 32 + kk) * DOUT_ + n]);
  }
}

// ---------------- kernel A: 3-NN + inverse-distance weights ----------------
// One query per thread; the whole wave scans the same candidate (LDS
// same-address broadcast, immediate ds offsets). grid: B*(N1/128) = 512
// blocks x 128 threads. Exact direct-form fp32 distance (selection is
// near-tie sensitive; expanded form would flip neighbors).

__global__ __launch_bounds__(128) void knn_kernel(
    const float* __restrict__ xyz1, const float* __restrict__ xyz2,
    int* __restrict__ idx_out, float* __restrict__ w_out) {
  __shared__ float4 xs4[N2_];  // 16 KB
  const int b = blockIdx.x >> 5;
  const int chunk = blockIdx.x & 31;
  const float* p2 = xyz2 + (size_t)b * N2_ * 3;
  for (int i = threadIdx.x; i < N2_; i += 128) {
    const float* s = p2 + 3 * i;
    xs4[i] = make_float4(s[0], s[1], s[2], 0.0f);
  }
  __syncthreads();

  const int row = b * N1_ + chunk * 128 + threadIdx.x;
  const float* p1 = xyz1 + (size_t)row * 3;
  const float x1 = p1[0], y1 = p1[1], z1 = p1[2];

  float s0 = 3.0e38f, s1 = 3.0e38f, s2 = 3.0e38f;
  int i0 = 0, i1 = 0, i2 = 0;

  for (int o = 0; o < N2_; o += 16) {
#pragma unroll
    for (int i = 0; i < 16; ++i) {
      float4 qv = xs4[o + i];  // wave-uniform addr -> broadcast
      float dx = x1 - qv.x;
      float dy = y1 - qv.y;
      float dz = z1 - qv.z;
      float d = dx * dx + dy * dy + dz * dz;
      // sorted-insert: values via fmed3/min (exact), indices via cmp+sel
      bool c0 = d < s0, c1 = d < s1, c2 = d < s2;
      float ns2 = __builtin_amdgcn_fmed3f(d, s1, s2);
      float ns1 = __builtin_amdgcn_fmed3f(d, s0, s1);
      float ns0 = fminf(d, s0);
      int p = o + i;
      i2 = c1 ? i1 : (c2 ? p : i2);
      i1 = c0 ? i0 : (c1 ? p : i1);
      i0 = c0 ? p : i0;
      s0 = ns0; s1 = ns1; s2 = ns2;
    }
  }

  float r0 = 1.0f / fmaxf(s0, 1e-10f);
  float r1 = 1.0f / fmaxf(s1, 1e-10f);
  float r2 = 1.0f / fmaxf(s2, 1e-10f);
  float s = 1.0f / (r0 + r1 + r2);
  int base = row * 3;
  idx_out[base + 0] = i0;
  idx_out[base + 1] = i1;
  idx_out[base + 2] = i2;
  w_out[base + 0] = r0 * s;
  w_out[base + 1] = r1 * s;
  w_out[base + 2] = r2 * s;
}

// ---------------- fused: build + GEMM1 + GEMM2 ----------------
// 64 rows/block, 1024 blocks, 512 threads (8 waves). wave (wm=w&1,
// wn=w>>1) owns rows [32wm,32wm+32) x cols [64wn,64wn+64). 50 KB LDS ->
// 3 blocks/CU = 24 waves/CU (TLP hides build gathers + W L2 latency).
// W b-frags single-buffered direct global loads from pre-swizzled arrays.
// No barriers inside K-loops.

__global__ __launch_bounds__(512, 6) void fused_kernel(
    const float* __restrict__ feat1, const float* __restrict__ feat2,
    const int* __restrict__ idx, const float* __restrict__ w,
    const ushort_t* __restrict__ W1s, const float* __restrict__ b1,
    const ushort_t* __restrict__ W2s, const float* __restrict__ b2,
    float* __restrict__ out) {
  __shared__ ushort_t As[64 * ASTRIDE];  // 50176 B
  const int tid = threadIdx.x;
  const int wave = tid >> 6;
  const int lane = tid & 63;
  const int m = lane & 15;
  const int q = lane >> 4;
  const int wm = wave & 1;
  const int wn = wave >> 1;
  const int row0 = blockIdx.x * 64;
  const int b = row0 >> 12;

  const int b_off = (wn * 64 + m) * 32 + q * 8;  // frag base in W1s/W2s

  // ---- build phase: 8 rows per wave, As row-major padded ----
#pragma unroll
  for (int it = 0; it < 8; ++it) {
    int rl = wave * 8 + it;
    int row = row0 + rl;
    const int* ip = idx + (size_t)row * 3;
    const float* wp = w + (size_t)row * 3;
    int i0 = ip[0], i1 = ip[1], i2 = ip[2];
    float w0 = wp[0], w1 = wp[1], w2 = wp[2];

    const float4* f0 = (const float4*)(feat2 + ((size_t)b * N2_ + i0) * C2_);
    const float4* f1 = (const float4*)(feat2 + ((size_t)b * N2_ + i1) * C2_);
    const float4* f2 = (const float4*)(feat2 + ((size_t)b * N2_ + i2) * C2_);
    float4 a = f0[lane];
    float4 c = f1[lane];
    float4 d = f2[lane];
    float vx = w0 * a.x + w1 * c.x + w2 * d.x;
    float vy = w0 * a.y + w1 * c.y + w2 * d.y;
    float vz = w0 * a.z + w1 * c.z + w2 * d.z;
    float vw = w0 * a.w + w1 * c.w + w2 * d.w;
    uint_t lo = (uint_t)f2bf(vx) | ((uint_t)f2bf(vy) << 16);
    uint_t hi = (uint_t)f2bf(vz) | ((uint_t)f2bf(vw) << 16);
    *(uint2*)&As[rl * ASTRIDE + 4 * lane] = make_uint2(lo, hi);

    float2 t1 = ((const float2*)(feat1 + (size_t)row * C1_))[lane];
    uint_t pk = (uint_t)f2bf(t1.x) | ((uint_t)f2bf(t1.y) << 16);
    *(uint_t*)&As[rl * ASTRIDE + 256 + 2 * lane] = pk;
  }
  __syncthreads();

  // ---- GEMM1: K = 384 (12 t-tiles), no barriers ----
  floatx4 acc[2][4];
#pragma unroll
  for (int i = 0; i < 2; ++i)
#pragma unroll
    for (int j = 0; j < 4; ++j) acc[i][j] = (floatx4)0.0f;

#pragma unroll 2
  for (int t = 0; t < 12; ++t) {
    bf16x8 bfr[4], af[2];
#pragma unroll
    for (int j = 0; j < 4; ++j)
      bfr[j] = *(const bf16x8*)(W1s + (size_t)t * 8192 + b_off + j * 512);
#pragma unroll
    for (int i = 0; i < 2; ++i)
      af[i] = *(const bf16x8*)&As[(wm * 32 + m + 16 * i) * ASTRIDE + t * 32 + q * 8];
#pragma unroll
    for (int i = 0; i < 2; ++i)
#pragma unroll
      for (int j = 0; j < 4; ++j)
        acc[i][j] = __builtin_amdgcn_mfma_f32_16x16x32_bf16(af[i], bfr[j],
                                                            acc[i][j], 0, 0, 0);
  }
  __syncthreads();  // all As reads done before HS overwrites the region

  // ---- epilogue1: bias + relu -> bf16 HS (row-major padded, aliases As) ----
  ushort_t* HS = As;
#pragma unroll
  for (int j = 0; j < 4; ++j) {
    int col = wn * 64 + j * 16 + m;
    float bv = b1[col];
#pragma unroll
    for (int i = 0; i < 2; ++i)
#pragma unroll
      for (int r = 0; r < 4; ++r) {
        int row = wm * 32 + i * 16 + q * 4 + r;
        float v = acc[i][j][r] + bv;
        v = v > 0.0f ? v : 0.0f;
        HS[row * HSTRIDE + col] = f2bf(v);
      }
  }
  __syncthreads();

  // ---- GEMM2: K = 256 (8 t-tiles), a-frags from HS, no barriers ----
  floatx4 acc2[2][4];
#pragma unroll
  for (int i = 0; i < 2; ++i)
#pragma unroll
    for (int j = 0; j < 4; ++j) acc2[i][j] = (floatx4)0.0f;

#pragma unroll 2
  for (int t = 0; t < 8; ++t) {
    bf16x8 bfr[4], af[2];
#pragma unroll
    for (int j = 0; j < 4; ++j)
      bfr[j] = *(const bf16x8*)(W2s + (size_t)t * 8192 + b_off + j * 512);
#pragma unroll
    for (int i = 0; i < 2; ++i)
      af[i] = *(const bf16x8*)&HS[(wm * 32 + m + 16 * i) * HSTRIDE + t * 32 + q * 8];
#pragma unroll
    for (int i = 0; i < 2; ++i)
#pragma unroll
      for (int j = 0; j < 4; ++j)
        acc2[i][j] = __builtin_amdgcn_mfma_f32_16x16x32_bf16(af[i], bfr[j],
                                                             acc2[i][j], 0, 0, 0);
  }

  // ---- epilogue2: bias + relu -> fp32 out ----
#pragma unroll
  for (int j = 0; j < 4; ++j) {
    int col = wn * 64 + j * 16 + m;
    float bv = b2[col];
#pragma unroll
    for (int i = 0; i < 2; ++i)
#pragma unroll
      for (int r = 0; r < 4; ++r) {
        int row = wm * 32 + i * 16 + q * 4 + r;
        float v = acc2[i][j][r] + bv;
        v = v > 0.0f ? v : 0.0f;
        out[(size_t)(row0 + row) * DOUT_ + col] = v;
      }
  }
}

// ---------------- workspace layout ----------------

constexpr size_t OFF_W1S = 0;                    // 256*384*2 = 196608
constexpr size_t OFF_W2S = OFF_W1S + 196608;     // 256*256*2 = 131072
constexpr size_t OFF_IDX = OFF_W2S + 131072;     // 65536*3*4 = 786432
constexpr size_t OFF_W = OFF_IDX + 786432;       // 65536*3*4 = 786432
constexpr size_t WS_TOTAL = OFF_W + 786432;      // ~1.9 MB

extern "C" void kernel_launch(void* const* d_in, const int* in_sizes, int n_in,
                              void* d_out, int out_size, void* d_ws, size_t ws_size,
                              hipStream_t stream) {
  const float* xyz1 = (const float*)d_in[0];
  const float* feat1 = (const float*)d_in[1];
  const float* xyz2 = (const float*)d_in[2];
  const float* feat2 = (const float*)d_in[3];
  const float* W1 = (const float*)d_in[4];
  const float* b1 = (const float*)d_in[5];
  const float* W2 = (const float*)d_in[6];
  const float* b2 = (const float*)d_in[7];

  if (ws_size < WS_TOTAL) return;

  char* ws = (char*)d_ws;
  ushort_t* W1s = (ushort_t*)(ws + OFF_W1S);
  ushort_t* W2s = (ushort_t*)(ws + OFF_W2S);
  int* idx = (int*)(ws + OFF_IDX);
  float* w = (float*)(ws + OFF_W);

  prep_kernel<<<384, 256, 0, stream>>>(W1, W2, W1s, W2s);
  knn_kernel<<<B_ * (N1_ / 128), 128, 0, stream>>>(xyz1, xyz2, idx, w);
  fused_kernel<<<M_ / 64, 512, 0, stream>>>(feat1, feat2, idx, w, W1s, b1, W2s,
                                            b2, (float*)d_out);
}

// Round 6
// 193.378 us; speedup vs baseline: 1.2069x; 1.2069x over previous
//
#include <hip/hip_runtime.h>
#include <cstdint>
#include <cstddef>

typedef unsigned short ushort_t;
typedef unsigned int uint_t;

typedef __bf16 bf16x8 __attribute__((ext_vector_type(8)));
typedef float floatx4 __attribute__((ext_vector_type(4)));

#define B_ 16
#define N1_ 4096
#define N2_ 1024
#define C1_ 128
#define C2_ 256
#define DIN_ 384
#define DOUT_ 256
#define M_ (B_ * N1_)  // 65536

// As: row-major [64 rows][384 cols] bf16, +8 elem row pad -> 392 elems.
#define ASTRIDE 392
// HS: row-major [64 rows][256 cols] bf16, +8 elem row pad -> 264 elems.
// Aliases the front of As.
#define HSTRIDE 264

// ---------------- helpers ----------------

__device__ __forceinline__ ushort_t f2bf(float f) {
  unsigned int u = __builtin_bit_cast(unsigned int, f);
  u = (u + 0x7fffu + ((u >> 16) & 1u)) >> 16;  // RNE
  return (ushort_t)u;
}

// ---------------- kernel P: weight swizzle + bf16 convert ----------------
// W1s[t][n][kk] = bf16(W1[t*32+kk][n]) — exact B-fragment order.

__global__ __launch_bounds__(256) void prep_kernel(
    const float* __restrict__ W1, const float* __restrict__ W2,
    ushort_t* __restrict__ W1s, ushort_t* __restrict__ W2s) {
  int e = blockIdx.x * 256 + threadIdx.x;
  if (e < DOUT_ * DIN_) {  // 98304
    int kk = e & 31, n = (e >> 5) & 255, t = e >> 13;
    W1s[e] = f2bf(W1[(size_t)(t * 32 + kk) * DOUT_ + n]);
  }
  if (e < DOUT_ * DOUT_) {  // 65536
    int kk = e & 31, n = (e >> 5) & 255, t = e >> 13;
    W2s[e] = f2bf(W2[(size_t)(t * 32 + kk) * DOUT_ + n]);
  }
}

// ---------------- kernel A: 3-NN + inverse-distance weights ----------------
// Round-2 structure (known-good, issue-bound at 87% VALUBusy):
// 2048 blocks x 256 thr, 8 sub-threads/query, 8192 waves total.

__device__ __forceinline__ void ins_exact(float& s0, float& s1, float& s2,
                                          int& i0, int& i1, int& i2,
                                          float d, int p) {
  float ns2 = __builtin_amdgcn_fmed3f(d, s1, s2);
  float ns1 = __builtin_amdgcn_fmed3f(d, s0, s1);
  float ns0 = fminf(d, s0);
  bool c0 = d < s0, c1 = d < s1, c2 = d < s2;
  i2 = c1 ? i1 : (c2 ? p : i2);
  i1 = c0 ? i0 : (c1 ? p : i1);
  i0 = c0 ? p : i0;
  s0 = ns0; s1 = ns1; s2 = ns2;
}

__device__ __forceinline__ void ins_merge(float& s0, float& s1, float& s2,
                                          int& i0, int& i1, int& i2,
                                          float e, int j) {
  bool t0 = (e < s0) || (e == s0 && j < i0);
  bool t1 = (e < s1) || (e == s1 && j < i1);
  bool t2 = (e < s2) || (e == s2 && j < i2);
  s2 = t1 ? s1 : (t2 ? e : s2);
  i2 = t1 ? i1 : (t2 ? j : i2);
  s1 = t0 ? s0 : (t1 ? e : s1);
  i1 = t0 ? i0 : (t1 ? j : i1);
  s0 = t0 ? e : s0;
  i0 = t0 ? j : i0;
}

__global__ __launch_bounds__(256) void knn_kernel(
    const float* __restrict__ xyz1, const float* __restrict__ xyz2,
    int* __restrict__ idx_out, float* __restrict__ w_out) {
  __shared__ float4 xs4[N2_];  // 16 KB
  int b = blockIdx.x >> 7;
  int n1base = (blockIdx.x & 127) << 5;
  const float* p2 = xyz2 + (size_t)b * N2_ * 3;
  for (int i = threadIdx.x; i < N2_; i += 256) {
    const float* s = p2 + 3 * i;
    xs4[i] = make_float4(s[0], s[1], s[2], 0.0f);
  }
  __syncthreads();

  int g = threadIdx.x >> 3;
  int sub = threadIdx.x & 7;
  int row = b * N1_ + n1base + g;
  const float* p1 = xyz1 + (size_t)row * 3;
  float x1 = p1[0], y1 = p1[1], z1 = p1[2];

  float s0 = 3.0e38f, s1 = 3.0e38f, s2 = 3.0e38f;
  int i0 = 0, i1 = 0, i2 = 0;

  int p = sub;
#pragma unroll 8
  for (int t = 0; t < N2_ / 8; ++t) {
    float4 qv = xs4[p];
    float dx = x1 - qv.x;
    float dy = y1 - qv.y;
    float dz = z1 - qv.z;
    float d = dx * dx + dy * dy + dz * dz;
    ins_exact(s0, s1, s2, i0, i1, i2, d, p);
    p += 8;
  }

#pragma unroll
  for (int mm = 1; mm <= 4; mm <<= 1) {
    float e0 = __shfl_xor(s0, mm), e1 = __shfl_xor(s1, mm), e2 = __shfl_xor(s2, mm);
    int j0 = __shfl_xor(i0, mm), j1 = __shfl_xor(i1, mm), j2 = __shfl_xor(i2, mm);
    ins_merge(s0, s1, s2, i0, i1, i2, e0, j0);
    ins_merge(s0, s1, s2, i0, i1, i2, e1, j1);
    ins_merge(s0, s1, s2, i0, i1, i2, e2, j2);
  }

  if (sub == 0) {
    float r0 = 1.0f / fmaxf(s0, 1e-10f);
    float r1 = 1.0f / fmaxf(s1, 1e-10f);
    float r2 = 1.0f / fmaxf(s2, 1e-10f);
    float s = 1.0f / (r0 + r1 + r2);
    int base = row * 3;
    idx_out[base + 0] = i0;
    idx_out[base + 1] = i1;
    idx_out[base + 2] = i2;
    w_out[base + 0] = r0 * s;
    w_out[base + 1] = r1 * s;
    w_out[base + 2] = r2 * s;
  }
}

// ---------------- fused: build + GEMM1 + GEMM2 ----------------
// Round-4 structure (4 waves x 256 thr, 64 rows/block, W-frag register
// double-buffer, no barriers in K-loops) + XCD-aware block swizzle:
// rb = (bi&7)*128 + (bi>>3) clusters each XCD's blocks onto 2 batches so
// the feat2 gather set (2.1 MB) is L2-resident per XCD.

__global__ __launch_bounds__(256, 3) void fused_kernel(
    const float* __restrict__ feat1, const float* __restrict__ feat2,
    const int* __restrict__ idx, const float* __restrict__ w,
    const ushort_t* __restrict__ W1s, const float* __restrict__ b1,
    const ushort_t* __restrict__ W2s, const float* __restrict__ b2,
    float* __restrict__ out) {
  __shared__ ushort_t As[64 * ASTRIDE];  // 50176 B
  const int tid = threadIdx.x;
  const int wave = tid >> 6;
  const int lane = tid & 63;
  const int m = lane & 15;
  const int q = lane >> 4;
  // XCD swizzle: round-robin dispatch sends bi%8 to XCD (bi&7); give each
  // XCD a contiguous 128-block (2-batch) range.
  const int rb = (blockIdx.x & 7) * 128 + (blockIdx.x >> 3);
  const int row0 = rb * 64;
  const int b = row0 >> 12;

  const int b_off = (wave * 64 + m) * 32 + q * 8;  // frag base in W1s/W2s

  // prefetch first W1 b-frags before anything else (independent of build)
  bf16x8 bf0[4], bf1[4];
#pragma unroll
  for (int j = 0; j < 4; ++j) bf0[j] = *(const bf16x8*)(W1s + b_off + j * 512);

  // ---- build phase: As[row][col], row-major padded ----
#pragma unroll 8
  for (int it = 0; it < 16; ++it) {
    int rl = wave * 16 + it;
    int row = row0 + rl;
    const int* ip = idx + (size_t)row * 3;
    const float* wp = w + (size_t)row * 3;
    int i0 = ip[0], i1 = ip[1], i2 = ip[2];
    float w0 = wp[0], w1 = wp[1], w2 = wp[2];

    const float4* f0 = (const float4*)(feat2 + ((size_t)b * N2_ + i0) * C2_);
    const float4* f1 = (const float4*)(feat2 + ((size_t)b * N2_ + i1) * C2_);
    const float4* f2 = (const float4*)(feat2 + ((size_t)b * N2_ + i2) * C2_);
    float4 a = f0[lane];
    float4 c = f1[lane];
    float4 d = f2[lane];
    float vx = w0 * a.x + w1 * c.x + w2 * d.x;
    float vy = w0 * a.y + w1 * c.y + w2 * d.y;
    float vz = w0 * a.z + w1 * c.z + w2 * d.z;
    float vw = w0 * a.w + w1 * c.w + w2 * d.w;
    uint_t lo = (uint_t)f2bf(vx) | ((uint_t)f2bf(vy) << 16);
    uint_t hi = (uint_t)f2bf(vz) | ((uint_t)f2bf(vw) << 16);
    *(uint2*)&As[rl * ASTRIDE + 4 * lane] = make_uint2(lo, hi);

    float2 t1 = ((const float2*)(feat1 + (size_t)row * C1_))[lane];
    uint_t pk = (uint_t)f2bf(t1.x) | ((uint_t)f2bf(t1.y) << 16);
    *(uint_t*)&As[rl * ASTRIDE + 256 + 2 * lane] = pk;
  }
  __syncthreads();

  // ---- GEMM1: K = 384 (12 t-tiles), W dbuf, no barriers ----
  floatx4 acc[4][4];
#pragma unroll
  for (int i = 0; i < 4; ++i)
#pragma unroll
    for (int j = 0; j < 4; ++j) acc[i][j] = (floatx4)0.0f;

  {
    bf16x8 af[4];
#pragma unroll
    for (int t = 0; t < 12; t += 2) {
#pragma unroll
      for (int j = 0; j < 4; ++j)
        bf1[j] = *(const bf16x8*)(W1s + (size_t)(t + 1) * 8192 + b_off + j * 512);
#pragma unroll
      for (int i = 0; i < 4; ++i)
        af[i] = *(const bf16x8*)&As[(m + 16 * i) * ASTRIDE + t * 32 + q * 8];
#pragma unroll
      for (int i = 0; i < 4; ++i)
#pragma unroll
        for (int j = 0; j < 4; ++j)
          acc[i][j] = __builtin_amdgcn_mfma_f32_16x16x32_bf16(af[i], bf0[j],
                                                              acc[i][j], 0, 0, 0);
      if (t + 2 < 12) {
#pragma unroll
        for (int j = 0; j < 4; ++j)
          bf0[j] = *(const bf16x8*)(W1s + (size_t)(t + 2) * 8192 + b_off + j * 512);
      }
#pragma unroll
      for (int i = 0; i < 4; ++i)
        af[i] = *(const bf16x8*)&As[(m + 16 * i) * ASTRIDE + (t + 1) * 32 + q * 8];
#pragma unroll
      for (int i = 0; i < 4; ++i)
#pragma unroll
        for (int j = 0; j < 4; ++j)
          acc[i][j] = __builtin_amdgcn_mfma_f32_16x16x32_bf16(af[i], bf1[j],
                                                              acc[i][j], 0, 0, 0);
    }
  }

  // prefetch first W2 b-frags (independent of epi1)
#pragma unroll
  for (int j = 0; j < 4; ++j) bf0[j] = *(const bf16x8*)(W2s + b_off + j * 512);

  __syncthreads();  // all As reads done before HS overwrites the region

  // ---- epilogue1: bias + relu -> bf16 HS (row-major padded, aliases As) ----
  ushort_t* HS = As;
#pragma unroll
  for (int j = 0; j < 4; ++j) {
    int col = wave * 64 + j * 16 + m;
    float bv = b1[col];
#pragma unroll
    for (int i = 0; i < 4; ++i)
#pragma unroll
      for (int r = 0; r < 4; ++r) {
        int row = i * 16 + q * 4 + r;
        float v = acc[i][j][r] + bv;
        v = v > 0.0f ? v : 0.0f;
        HS[row * HSTRIDE + col] = f2bf(v);
      }
  }
  __syncthreads();

  // ---- GEMM2: K = 256 (8 t-tiles), a-frags from HS, W dbuf, no barriers ----
  floatx4 acc2[4][4];
#pragma unroll
  for (int i = 0; i < 4; ++i)
#pragma unroll
    for (int j = 0; j < 4; ++j) acc2[i][j] = (floatx4)0.0f;

  {
    bf16x8 af[4];
#pragma unroll
    for (int t = 0; t < 8; t += 2) {
#pragma unroll
      for (int j = 0; j < 4; ++j)
        bf1[j] = *(const bf16x8*)(W2s + (size_t)(t + 1) * 8192 + b_off + j * 512);
#pragma unroll
      for (int i = 0; i < 4; ++i)
        af[i] = *(const bf16x8*)&HS[(m + 16 * i) * HSTRIDE + t * 32 + q * 8];
#pragma unroll
      for (int i = 0; i < 4; ++i)
#pragma unroll
        for (int j = 0; j < 4; ++j)
          acc2[i][j] = __builtin_amdgcn_mfma_f32_16x16x32_bf16(af[i], bf0[j],
                                                               acc2[i][j], 0, 0, 0);
      if (t + 2 < 8) {
#pragma unroll
        for (int j = 0; j < 4; ++j)
          bf0[j] = *(const bf16x8*)(W2s + (size_t)(t + 2) * 8192 + b_off + j * 512);
      }
#pragma unroll
      for (int i = 0; i < 4; ++i)
        af[i] = *(const bf16x8*)&HS[(m + 16 * i) * HSTRIDE + (t + 1) * 32 + q * 8];
#pragma unroll
      for (int i = 0; i < 4; ++i)
#pragma unroll
        for (int j = 0; j < 4; ++j)
          acc2[i][j] = __builtin_amdgcn_mfma_f32_16x16x32_bf16(af[i], bf1[j],
                                                               acc2[i][j], 0, 0, 0);
    }
  }

  // ---- epilogue2: bias + relu -> fp32 out ----
#pragma unroll
  for (int j = 0; j < 4; ++j) {
    int col = wave * 64 + j * 16 + m;
    float bv = b2[col];
#pragma unroll
    for (int i = 0; i < 4; ++i)
#pragma unroll
      for (int r = 0; r < 4; ++r) {
        int row = i * 16 + q * 4 + r;
        float v = acc2[i][j][r] + bv;
        v = v > 0.0f ? v : 0.0f;
        out[(size_t)(row0 + row) * DOUT_ + col] = v;
      }
  }
}

// ---------------- workspace layout ----------------

constexpr size_t OFF_W1S = 0;                    // 256*384*2 = 196608
constexpr size_t OFF_W2S = OFF_W1S + 196608;     // 256*256*2 = 131072
constexpr size_t OFF_IDX = OFF_W2S + 131072;     // 65536*3*4 = 786432
constexpr size_t OFF_W = OFF_IDX + 786432;       // 65536*3*4 = 786432
constexpr size_t WS_TOTAL = OFF_W + 786432;      // ~1.9 MB

extern "C" void kernel_launch(void* const* d_in, const int* in_sizes, int n_in,
                              void* d_out, int out_size, void* d_ws, size_t ws_size,
                              hipStream_t stream) {
  const float* xyz1 = (const float*)d_in[0];
  const float* feat1 = (const float*)d_in[1];
  const float* xyz2 = (const float*)d_in[2];
  const float* feat2 = (const float*)d_in[3];
  const float* W1 = (const float*)d_in[4];
  const float* b1 = (const float*)d_in[5];
  const float* W2 = (const float*)d_in[6];
  const float* b2 = (const float*)d_in[7];

  if (ws_size < WS_TOTAL) return;

  char* ws = (char*)d_ws;
  ushort_t* W1s = (ushort_t*)(ws + OFF_W1S);
  ushort_t* W2s = (ushort_t*)(ws + OFF_W2S);
  int* idx = (int*)(ws + OFF_IDX);
  float* w = (float*)(ws + OFF_W);

  prep_kernel<<<384, 256, 0, stream>>>(W1, W2, W1s, W2s);
  knn_kernel<<<B_ * (N1_ / 32), 256, 0, stream>>>(xyz1, xyz2, idx, w);
  fused_kernel<<<M_ / 64, 256, 0, stream>>>(feat1, feat2, idx, w, W1s, b1, W2s,
                                            b2, (float*)d_out);
}